// Round 2
// baseline (503.443 us; speedup 1.0000x reference)
//
#include <hip/hip_runtime.h>

#define N_NODES 100000
#define D_FEAT 64
#define SCAN_THREADS 1024

// ---------- CSR build ----------

__global__ void deg_kernel(const int* __restrict__ row, int* __restrict__ deg, int E) {
    int i = blockIdx.x * blockDim.x + threadIdx.x;
    int stride = gridDim.x * blockDim.x;
    for (; i < E; i += stride) atomicAdd(&deg[row[i]], 1);
}

__global__ void dis_kernel(const int* __restrict__ deg, float* __restrict__ dis, int N) {
    int i = blockIdx.x * blockDim.x + threadIdx.x;
    if (i < N) {
        int d = deg[i];
        dis[i] = (d > 0) ? rsqrtf((float)d) : 0.0f;
    }
}

// Single-block exclusive scan over deg -> rowStart, cursor
__global__ void scan_kernel(const int* __restrict__ deg, int* __restrict__ rowStart,
                            int* __restrict__ cursor, int N, int E) {
    __shared__ int sums[SCAN_THREADS];
    int t = threadIdx.x;
    int chunk = (N + SCAN_THREADS - 1) / SCAN_THREADS;
    int lo = t * chunk;
    int hi = min(lo + chunk, N);
    int s = 0;
    for (int i = lo; i < hi; ++i) s += deg[i];
    sums[t] = s;
    __syncthreads();
    // Hillis-Steele inclusive scan
    for (int off = 1; off < SCAN_THREADS; off <<= 1) {
        int v = (t >= off) ? sums[t - off] : 0;
        __syncthreads();
        sums[t] += v;
        __syncthreads();
    }
    int base = (t == 0) ? 0 : sums[t - 1];
    for (int i = lo; i < hi; ++i) {
        rowStart[i] = base;
        cursor[i] = base;
        base += deg[i];
    }
    if (t == SCAN_THREADS - 1) rowStart[N] = E;
}

__global__ void fill_kernel(const int* __restrict__ row, const int* __restrict__ col,
                            int* __restrict__ cursor, int* __restrict__ csr_col, int E) {
    int i = blockIdx.x * blockDim.x + threadIdx.x;
    int stride = gridDim.x * blockDim.x;
    for (; i < E; i += stride) {
        int pos = atomicAdd(&cursor[row[i]], 1);
        csr_col[pos] = col[i];
    }
}

// ---------- SpMM: one wave per row, lane = feature ----------

__global__ void spmm_kernel(const float* __restrict__ x,
                            const int* __restrict__ rowStart,
                            const int* __restrict__ csr_col,
                            const float* __restrict__ dis,
                            float* __restrict__ out, int N) {
    int wid = (int)((blockIdx.x * (long long)blockDim.x + threadIdx.x) >> 6);
    int lane = threadIdx.x & 63;
    if (wid >= N) return;
    int s = rowStart[wid];
    int e = rowStart[wid + 1];
    float acc = 0.0f;
    int j = s;
    for (; j + 3 < e; j += 4) {
        int c0 = csr_col[j];
        int c1 = csr_col[j + 1];
        int c2 = csr_col[j + 2];
        int c3 = csr_col[j + 3];
        float d0 = dis[c0], d1 = dis[c1], d2 = dis[c2], d3 = dis[c3];
        float x0 = x[(long long)c0 * D_FEAT + lane];
        float x1 = x[(long long)c1 * D_FEAT + lane];
        float x2 = x[(long long)c2 * D_FEAT + lane];
        float x3 = x[(long long)c3 * D_FEAT + lane];
        acc += d0 * x0 + d1 * x1 + d2 * x2 + d3 * x3;
    }
    for (; j < e; ++j) {
        int c = csr_col[j];
        acc += dis[c] * x[(long long)c * D_FEAT + lane];
    }
    out[(long long)wid * D_FEAT + lane] = dis[wid] * acc;
}

// ---------- fallback (ws too small): round-1 scatter path ----------

__global__ void fb_deg_kernel(const int* __restrict__ row, float* __restrict__ deg, int E) {
    int i = blockIdx.x * blockDim.x + threadIdx.x;
    int stride = gridDim.x * blockDim.x;
    for (; i < E; i += stride) atomicAdd(&deg[row[i]], 1.0f);
}
__global__ void fb_dis_kernel(float* __restrict__ deg, int N) {
    int i = blockIdx.x * blockDim.x + threadIdx.x;
    if (i < N) { float d = deg[i]; deg[i] = (d > 0.0f) ? rsqrtf(d) : 0.0f; }
}
__global__ void fb_scatter_kernel(const float* __restrict__ x, const int* __restrict__ row,
                                  const int* __restrict__ col, const float* __restrict__ dis,
                                  float* __restrict__ out, long long total) {
    long long i = (long long)blockIdx.x * blockDim.x + threadIdx.x;
    long long stride = (long long)gridDim.x * blockDim.x;
    for (; i < total; i += stride) {
        int e = (int)(i >> 6);
        int d = (int)(i & 63);
        int r = row[e];
        int c = col[e];
        atomicAdd(&out[(long long)r * D_FEAT + d], dis[r] * dis[c] * x[(long long)c * D_FEAT + d]);
    }
}

extern "C" void kernel_launch(void* const* d_in, const int* in_sizes, int n_in,
                              void* d_out, int out_size, void* d_ws, size_t ws_size,
                              hipStream_t stream) {
    const float* x  = (const float*)d_in[0];
    const int*   ei = (const int*)d_in[1];
    int E = in_sizes[1] / 2;
    const int* row = ei;
    const int* col = ei + E;
    float* out = (float*)d_out;
    const int N = N_NODES;

    size_t need = (size_t)(3 * N + 1 + N + E) * 4;  // deg, rowStart(N+1), cursor, dis, csr_col
    if (ws_size < need) {
        // fallback: atomic scatter
        float* deg = (float*)d_ws;
        hipMemsetAsync(out, 0, (size_t)out_size * sizeof(float), stream);
        hipMemsetAsync(deg, 0, (size_t)N * sizeof(float), stream);
        fb_deg_kernel<<<2048, 256, 0, stream>>>(row, deg, E);
        fb_dis_kernel<<<(N + 255) / 256, 256, 0, stream>>>(deg, N);
        fb_scatter_kernel<<<4096, 256, 0, stream>>>(x, row, col, deg, out, (long long)E * D_FEAT);
        return;
    }

    char* ws = (char*)d_ws;
    int*   deg      = (int*)ws;                         ws += (size_t)N * 4;
    int*   rowStart = (int*)ws;                         ws += (size_t)(N + 1) * 4;
    int*   cursor   = (int*)ws;                         ws += (size_t)N * 4;
    float* dis      = (float*)ws;                       ws += (size_t)N * 4;
    int*   csr_col  = (int*)ws;

    hipMemsetAsync(deg, 0, (size_t)N * sizeof(int), stream);
    deg_kernel<<<2048, 256, 0, stream>>>(row, deg, E);
    dis_kernel<<<(N + 255) / 256, 256, 0, stream>>>(deg, dis, N);
    scan_kernel<<<1, SCAN_THREADS, 0, stream>>>(deg, rowStart, cursor, N, E);
    fill_kernel<<<2048, 256, 0, stream>>>(row, col, cursor, csr_col, E);

    int waves_per_block = 4;  // 256 threads
    int blocks = (N + waves_per_block - 1) / waves_per_block;
    spmm_kernel<<<blocks, 256, 0, stream>>>(x, rowStart, csr_col, dis, out, N);
}

// Round 3
// 291.384 us; speedup vs baseline: 1.7278x; 1.7278x over previous
//
#include <hip/hip_runtime.h>

#define N_NODES 100000
#define D_FEAT 64
#define SCAN_BLOCKS 256
#define SCAN_TPB 256

// ---------- CSR build ----------

__global__ void deg_kernel(const int* __restrict__ row, int* __restrict__ deg, int E) {
    int i = blockIdx.x * blockDim.x + threadIdx.x;
    int stride = gridDim.x * blockDim.x;
    for (; i < E; i += stride) atomicAdd(&deg[row[i]], 1);
}

__global__ void dis_kernel(const int* __restrict__ deg, float* __restrict__ dis, int N) {
    int i = blockIdx.x * blockDim.x + threadIdx.x;
    if (i < N) {
        int d = deg[i];
        dis[i] = (d > 0) ? rsqrtf((float)d) : 0.0f;
    }
}

// ---------- two-level scan (deterministic) ----------
// Partition: block b owns [b*CB, min((b+1)*CB, N)), thread t owns TB consecutive
// elements within that. CB = ceil(N/SCAN_BLOCKS), TB = ceil(CB/SCAN_TPB).

__global__ void scan1_kernel(const int* __restrict__ deg, int* __restrict__ blockSums, int N) {
    __shared__ int sums[SCAN_TPB];
    int b = blockIdx.x, t = threadIdx.x;
    int CB = (N + SCAN_BLOCKS - 1) / SCAN_BLOCKS;
    int TB = (CB + SCAN_TPB - 1) / SCAN_TPB;
    int lo = b * CB + t * TB;
    int hi = min(lo + TB, min((b + 1) * CB, N));
    int s = 0;
    for (int i = lo; i < hi; ++i) s += deg[i];
    sums[t] = s;
    __syncthreads();
    for (int off = SCAN_TPB / 2; off > 0; off >>= 1) {
        if (t < off) sums[t] += sums[t + off];
        __syncthreads();
    }
    if (t == 0) blockSums[b] = sums[0];
}

__global__ void scan2_kernel(int* __restrict__ blockSums, int* __restrict__ blockOffs) {
    __shared__ int sums[SCAN_BLOCKS];
    int t = threadIdx.x;
    sums[t] = blockSums[t];
    __syncthreads();
    for (int off = 1; off < SCAN_BLOCKS; off <<= 1) {
        int v = (t >= off) ? sums[t - off] : 0;
        __syncthreads();
        sums[t] += v;
        __syncthreads();
    }
    blockOffs[t] = (t == 0) ? 0 : sums[t - 1];  // exclusive
}

__global__ void scan3_kernel(const int* __restrict__ deg, const int* __restrict__ blockOffs,
                             int* __restrict__ rowStart, int* __restrict__ cursor,
                             int N, int E) {
    __shared__ int sums[SCAN_TPB];
    int b = blockIdx.x, t = threadIdx.x;
    int CB = (N + SCAN_BLOCKS - 1) / SCAN_BLOCKS;
    int TB = (CB + SCAN_TPB - 1) / SCAN_TPB;
    int lo = b * CB + t * TB;
    int hi = min(lo + TB, min((b + 1) * CB, N));
    int s = 0;
    for (int i = lo; i < hi; ++i) s += deg[i];
    sums[t] = s;
    __syncthreads();
    for (int off = 1; off < SCAN_TPB; off <<= 1) {
        int v = (t >= off) ? sums[t - off] : 0;
        __syncthreads();
        sums[t] += v;
        __syncthreads();
    }
    int base = blockOffs[b] + ((t == 0) ? 0 : sums[t - 1]);
    for (int i = lo; i < hi; ++i) {
        rowStart[i] = base;
        cursor[i] = base;
        base += deg[i];
    }
    if (b == 0 && t == 0) rowStart[N] = E;
}

__global__ void fill_kernel(const int* __restrict__ row, const int* __restrict__ col,
                            int* __restrict__ cursor, int* __restrict__ csr_col, int E) {
    int i = blockIdx.x * blockDim.x + threadIdx.x;
    int stride = gridDim.x * blockDim.x;
    for (; i < E; i += stride) {
        int pos = atomicAdd(&cursor[row[i]], 1);
        csr_col[pos] = col[i];
    }
}

// ---------- SpMM: one wave per row, lane = feature ----------

__global__ void spmm_kernel(const float* __restrict__ x,
                            const int* __restrict__ rowStart,
                            const int* __restrict__ csr_col,
                            const float* __restrict__ dis,
                            float* __restrict__ out, int N) {
    int wid = (int)((blockIdx.x * (long long)blockDim.x + threadIdx.x) >> 6);
    int lane = threadIdx.x & 63;
    if (wid >= N) return;
    int s = rowStart[wid];
    int e = rowStart[wid + 1];
    float acc = 0.0f;
    int j = s;
    for (; j + 3 < e; j += 4) {
        int c0 = csr_col[j];
        int c1 = csr_col[j + 1];
        int c2 = csr_col[j + 2];
        int c3 = csr_col[j + 3];
        float d0 = dis[c0], d1 = dis[c1], d2 = dis[c2], d3 = dis[c3];
        float x0 = x[(long long)c0 * D_FEAT + lane];
        float x1 = x[(long long)c1 * D_FEAT + lane];
        float x2 = x[(long long)c2 * D_FEAT + lane];
        float x3 = x[(long long)c3 * D_FEAT + lane];
        acc += d0 * x0 + d1 * x1 + d2 * x2 + d3 * x3;
    }
    for (; j < e; ++j) {
        int c = csr_col[j];
        acc += dis[c] * x[(long long)c * D_FEAT + lane];
    }
    out[(long long)wid * D_FEAT + lane] = dis[wid] * acc;
}

// ---------- fallback (ws too small): atomic scatter path ----------

__global__ void fb_deg_kernel(const int* __restrict__ row, float* __restrict__ deg, int E) {
    int i = blockIdx.x * blockDim.x + threadIdx.x;
    int stride = gridDim.x * blockDim.x;
    for (; i < E; i += stride) atomicAdd(&deg[row[i]], 1.0f);
}
__global__ void fb_dis_kernel(float* __restrict__ deg, int N) {
    int i = blockIdx.x * blockDim.x + threadIdx.x;
    if (i < N) { float d = deg[i]; deg[i] = (d > 0.0f) ? rsqrtf(d) : 0.0f; }
}
__global__ void fb_scatter_kernel(const float* __restrict__ x, const int* __restrict__ row,
                                  const int* __restrict__ col, const float* __restrict__ dis,
                                  float* __restrict__ out, long long total) {
    long long i = (long long)blockIdx.x * blockDim.x + threadIdx.x;
    long long stride = (long long)gridDim.x * blockDim.x;
    for (; i < total; i += stride) {
        int e = (int)(i >> 6);
        int d = (int)(i & 63);
        int r = row[e];
        int c = col[e];
        atomicAdd(&out[(long long)r * D_FEAT + d], dis[r] * dis[c] * x[(long long)c * D_FEAT + d]);
    }
}

extern "C" void kernel_launch(void* const* d_in, const int* in_sizes, int n_in,
                              void* d_out, int out_size, void* d_ws, size_t ws_size,
                              hipStream_t stream) {
    const float* x  = (const float*)d_in[0];
    const int*   ei = (const int*)d_in[1];
    int E = in_sizes[1] / 2;
    const int* row = ei;
    const int* col = ei + E;
    float* out = (float*)d_out;
    const int N = N_NODES;

    size_t need = ((size_t)(3 * N + 1 + N + E) + 2 * SCAN_BLOCKS) * 4;
    if (ws_size < need) {
        float* deg = (float*)d_ws;
        hipMemsetAsync(out, 0, (size_t)out_size * sizeof(float), stream);
        hipMemsetAsync(deg, 0, (size_t)N * sizeof(float), stream);
        fb_deg_kernel<<<2048, 256, 0, stream>>>(row, deg, E);
        fb_dis_kernel<<<(N + 255) / 256, 256, 0, stream>>>(deg, N);
        fb_scatter_kernel<<<4096, 256, 0, stream>>>(x, row, col, deg, out, (long long)E * D_FEAT);
        return;
    }

    char* ws = (char*)d_ws;
    int*   deg       = (int*)ws;    ws += (size_t)N * 4;
    int*   rowStart  = (int*)ws;    ws += (size_t)(N + 1) * 4;
    int*   cursor    = (int*)ws;    ws += (size_t)N * 4;
    float* dis       = (float*)ws;  ws += (size_t)N * 4;
    int*   blockSums = (int*)ws;    ws += (size_t)SCAN_BLOCKS * 4;
    int*   blockOffs = (int*)ws;    ws += (size_t)SCAN_BLOCKS * 4;
    int*   csr_col   = (int*)ws;

    hipMemsetAsync(deg, 0, (size_t)N * sizeof(int), stream);
    deg_kernel<<<2048, 256, 0, stream>>>(row, deg, E);
    dis_kernel<<<(N + 255) / 256, 256, 0, stream>>>(deg, dis, N);
    scan1_kernel<<<SCAN_BLOCKS, SCAN_TPB, 0, stream>>>(deg, blockSums, N);
    scan2_kernel<<<1, SCAN_BLOCKS, 0, stream>>>(blockSums, blockOffs);
    scan3_kernel<<<SCAN_BLOCKS, SCAN_TPB, 0, stream>>>(deg, blockOffs, rowStart, cursor, N, E);
    fill_kernel<<<2048, 256, 0, stream>>>(row, col, cursor, csr_col, E);

    int waves_per_block = 4;  // 256 threads
    int blocks = (N + waves_per_block - 1) / waves_per_block;
    spmm_kernel<<<blocks, 256, 0, stream>>>(x, rowStart, csr_col, dis, out, N);
}